// Round 14
// baseline (98.489 us; speedup 1.0000x reference)
//
#include <hip/hip_runtime.h>
#include <cstdint>
#include <cstddef>

typedef unsigned short u16;
typedef unsigned int   u32;
typedef __attribute__((ext_vector_type(4))) float f32x4;
typedef __attribute__((ext_vector_type(16))) float f32x16;
typedef __attribute__((ext_vector_type(8))) short bf16x8;
typedef __attribute__((ext_vector_type(2))) u32 u32x2;
typedef __attribute__((ext_vector_type(4))) u32 u32x4;

#define DEVI static __device__ __forceinline__
#define MFMA16(a,b,c) __builtin_amdgcn_mfma_f32_16x16x32_bf16((a),(b),(c),0,0,0)
#define MFMA32(a,b,c) __builtin_amdgcn_mfma_f32_32x32x16_bf16((a),(b),(c),0,0,0)
#define BAR()   __builtin_amdgcn_s_barrier()
#define CFENCE() asm volatile("" ::: "memory")

DEVI u16 f2b(float f) {
  u32 u = __builtin_bit_cast(u32, f);
  u32 r = u + 0x7fffu + ((u >> 16) & 1u);
  return (u16)(r >> 16);
}

DEVI u32 pkbf(float a, float b) {
  u32 r;
  asm("v_cvt_pk_bf16_f32 %0, %1, %2" : "=v"(r) : "v"(a), "v"(b));
  return r;
}

DEVI void load_lds16(const void* g, void* l) {
  __builtin_amdgcn_global_load_lds(
      (const __attribute__((address_space(1))) u32*)g,
      (__attribute__((address_space(3))) u32*)l, 16, 0, 0);
}

DEVI int perm_o(int o) { return 4 * (o & 63) + (o >> 6); }   // o' = h*64+i -> o = 4i+h

// ------------------------------------------------ merged: transpose(3072 blks) + weight prep(1280)
__global__ __launch_bounds__(256) void k_pre(
    const float* __restrict__ q, const float* __restrict__ k, const float* __restrict__ v,
    const float* __restrict__ wq, const float* __restrict__ wk,
    const float* __restrict__ wv, const float* __restrict__ wm,
    const float* __restrict__ bq, const float* __restrict__ bk, const float* __restrict__ bv,
    u16* __restrict__ xq, u16* __restrict__ xk, u16* __restrict__ xv,
    u16* __restrict__ WQ, u16* __restrict__ WK, u16* __restrict__ WV, u16* __restrict__ WM,
    float* __restrict__ BQ, float* __restrict__ BK, float* __restrict__ BV)
{
  __shared__ u16 tile[64][68];
  int blk = blockIdx.x, t = threadIdx.x;
  if (blk < 3072) {
    const int N = 2048, D = 256;
    int x = blk & 31, y = (blk >> 5) & 3, z = blk >> 7;
    int n0 = x * 64, c0 = y * 64;
    int b = z & 7, which = z >> 3;
    const float* src = (which == 0 ? q : which == 1 ? k : v) + (size_t)b * D * N;
    u16* dst = (which == 0 ? xq : which == 1 ? xk : xv) + (size_t)b * N * D;
    int cl = t >> 4, ng = t & 15;
#pragma unroll
    for (int cc = 0; cc < 4; ++cc) {
      int c = cl + 16 * cc;
      f32x4 val = *(const f32x4*)&src[(size_t)(c0 + c) * N + n0 + ng * 4];
#pragma unroll
      for (int j = 0; j < 4; ++j) tile[c][ng * 4 + j] = f2b(val[j]);
    }
    __syncthreads();
    int n = t & 63, cq = t >> 6;
    union { u16 s[16]; u32x4 v4[2]; } pk;
#pragma unroll
    for (int j = 0; j < 16; ++j) pk.s[j] = tile[cq * 16 + j][n];
    u32x4* o = (u32x4*)&dst[(size_t)(n0 + n) * D + c0 + cq * 16];
    o[0] = pk.v4[0];
    o[1] = pk.v4[1];
  } else {
    int p = blk - 3072;
    int row = p & 255, m = p >> 8;
    if (m == 0)      WQ[row * 256 + t] = f2b(wq[perm_o(row) * 256 + t]);
    else if (m == 1) WK[row * 256 + t] = f2b(wk[perm_o(row) * 256 + t]);
    else if (m == 2) WV[row * 256 + t] = f2b(wv[perm_o(row) * 256 + t]);
    else if (m == 3) WM[row * 256 + t] = f2b(wm[row * 256 + perm_o(t)]);
    else if (row == 0) {
      BQ[t] = bq[perm_o(t)];
      BK[t] = bk[perm_o(t)];
      BV[t] = bv[perm_o(t)];
    }
  }
}

// ------------------------------------------------ merged Q/K/V projection GEMM (3 x 1024 blocks)
// Q output PRE-SCALED by SC2. QK-proj decode has by FASTEST so the 4 blocks
// sharing an A-tile dispatch back-to-back (L2 reuse of the 2MB A panel).
__global__ __launch_bounds__(256, 4) void k_gemm3(
    const u16* __restrict__ XQ, const u16* __restrict__ XK, const u16* __restrict__ XV,
    const u16* __restrict__ WQm, const u16* __restrict__ WKm, const u16* __restrict__ WVm,
    const float* __restrict__ BQ, const float* __restrict__ BK, const float* __restrict__ BV,
    u16* __restrict__ QT, u16* __restrict__ KT, u16* __restrict__ VW)
{
  __shared__ u16 lA[2][64 * 64];
  __shared__ u16 lB[2][64 * 64];
  int gid = blockIdx.x, t = threadIdx.x;
  int wk = gid >> 10, rem = gid & 1023;
  int b = rem >> 7;
  int bx, by, epi;
  const u16 *Ab, *Bb;
  const float* bias;
  u16* outp;
  float osc = 1.0f;
  if (wk < 2) {
    by = rem & 3; bx = (rem >> 2) & 31;          // by fastest: A-tile reuse in L2
    Ab = (wk ? XK : XQ) + (size_t)b * (2048 * 256) + (size_t)bx * 64 * 256;
    Bb = (wk ? WKm : WQm) + (size_t)by * 64 * 256;
    bias = wk ? BK : BQ;
    outp = (wk ? KT : QT) + (size_t)b * (4L * 2048 * 64);
    epi = 0;
    if (wk == 0) osc = 0.18033688011112042f;     // SC2 baked into Q
  } else {
    bx = rem & 3; by = (rem >> 2) & 31;
    Ab = WVm + (size_t)bx * 64 * 256;
    Bb = XV + (size_t)b * (2048 * 256) + (size_t)by * 64 * 256;
    bias = BV;
    outp = VW + (size_t)b * (256L * 2048);
    epi = 1;
  }
  int l = t & 63, w = t >> 6, g = l >> 4, col = l & 15;
  int wr = w >> 1, wc = w & 1;
  f32x4 acc[2][2] = {};
  u32 sOf[2], sDs[2];
#pragma unroll
  for (int j = 0; j < 2; ++j) {
    int ci = t + 256 * j;
    int r = ci >> 3, c = ci & 7;
    sOf[j] = (u32)(r * 512 + ((c ^ (r & 7)) << 4));
    sDs[j] = (u32)(ci * 16);
  }
  auto stage = [&](int buf, int k0) {
#pragma unroll
    for (int j = 0; j < 2; ++j) {
      load_lds16((const char*)Ab + k0 * 2 + sOf[j], (char*)lA[buf] + sDs[j]);
      load_lds16((const char*)Bb + k0 * 2 + sOf[j], (char*)lB[buf] + sDs[j]);
    }
  };
  stage(0, 0);
  for (int s = 0; s < 4; ++s) {
    int cur = s & 1;
    if (s < 3) {
      stage(cur ^ 1, (s + 1) * 64);
      asm volatile("s_waitcnt vmcnt(4)" ::: "memory");
    } else {
      asm volatile("s_waitcnt vmcnt(0)" ::: "memory");
    }
    BAR(); CFENCE();
#pragma unroll
    for (int kc = 0; kc < 2; ++kc) {
      bf16x8 af[2], bfr[2];
#pragma unroll
      for (int mt = 0; mt < 2; ++mt) {
        int row = wr * 32 + mt * 16 + col;
        af[mt] = *(const bf16x8*)((const char*)lA[cur] + row * 128 + (((kc * 4 + g) ^ (row & 7)) << 4));
      }
#pragma unroll
      for (int nt = 0; nt < 2; ++nt) {
        int row = wc * 32 + nt * 16 + col;
        bfr[nt] = *(const bf16x8*)((const char*)lB[cur] + row * 128 + (((kc * 4 + g) ^ (row & 7)) << 4));
      }
#pragma unroll
      for (int mt = 0; mt < 2; ++mt)
#pragma unroll
        for (int nt = 0; nt < 2; ++nt)
          acc[mt][nt] = MFMA16(af[mt], bfr[nt], acc[mt][nt]);
    }
    if (s < 3) { CFENCE(); BAR(); }
  }
  if (epi == 0) {
#pragma unroll
    for (int nt = 0; nt < 2; ++nt) {
      int op = by * 64 + wc * 32 + nt * 16 + col;
      int hh = op >> 6, ii = op & 63;
      float bv = bias[op];
#pragma unroll
      for (int mt = 0; mt < 2; ++mt) {
        int nbase = bx * 64 + wr * 32 + mt * 16 + g * 4;
#pragma unroll
        for (int r = 0; r < 4; ++r)
          outp[((size_t)(hh * 2048 + nbase + r)) * 64 + ii] = f2b((acc[mt][nt][r] + bv) * osc);
      }
    }
  } else {
#pragma unroll
    for (int mt = 0; mt < 2; ++mt)
#pragma unroll
      for (int r = 0; r < 4; ++r) {
        int row = bx * 64 + wr * 32 + mt * 16 + g * 4 + r;
        float bv = bias[row];
#pragma unroll
        for (int nt = 0; nt < 2; ++nt) {
          int cn = by * 64 + wc * 32 + nt * 16 + col;
          outp[(size_t)row * 2048 + cn] = f2b(acc[mt][nt][r] + bv);
        }
      }
  }
}

// ---------------------------------------------------------------- final M-proj GEMM (f32 out)
__global__ __launch_bounds__(256, 4) void k_gemmM(
    const u16* __restrict__ A,
    const u16* __restrict__ Bm, long sB,
    const float* __restrict__ bias,
    float* __restrict__ out, long sOut)
{
  __shared__ u16 lA[2][64 * 64];
  __shared__ u16 lB[2][64 * 64];
  int t = threadIdx.x, b = blockIdx.z;
  const u16* Ab = A + (size_t)blockIdx.x * 64 * 256;
  const u16* Bb = Bm + (size_t)b * sB + (size_t)blockIdx.y * 64 * 256;
  int l = t & 63, w = t >> 6, g = l >> 4, col = l & 15;
  int wr = w >> 1, wc = w & 1;
  f32x4 acc[2][2] = {};
  u32 sOf[2], sDs[2];
#pragma unroll
  for (int j = 0; j < 2; ++j) {
    int ci = t + 256 * j;
    int r = ci >> 3, c = ci & 7;
    sOf[j] = (u32)(r * 512 + ((c ^ (r & 7)) << 4));
    sDs[j] = (u32)(ci * 16);
  }
  auto stage = [&](int buf, int k0) {
#pragma unroll
    for (int j = 0; j < 2; ++j) {
      load_lds16((const char*)Ab + k0 * 2 + sOf[j], (char*)lA[buf] + sDs[j]);
      load_lds16((const char*)Bb + k0 * 2 + sOf[j], (char*)lB[buf] + sDs[j]);
    }
  };
  stage(0, 0);
  for (int s = 0; s < 4; ++s) {
    int cur = s & 1;
    if (s < 3) {
      stage(cur ^ 1, (s + 1) * 64);
      asm volatile("s_waitcnt vmcnt(4)" ::: "memory");
    } else {
      asm volatile("s_waitcnt vmcnt(0)" ::: "memory");
    }
    BAR(); CFENCE();
#pragma unroll
    for (int kc = 0; kc < 2; ++kc) {
      bf16x8 af[2], bfr[2];
#pragma unroll
      for (int mt = 0; mt < 2; ++mt) {
        int row = wr * 32 + mt * 16 + col;
        af[mt] = *(const bf16x8*)((const char*)lA[cur] + row * 128 + (((kc * 4 + g) ^ (row & 7)) << 4));
      }
#pragma unroll
      for (int nt = 0; nt < 2; ++nt) {
        int row = wc * 32 + nt * 16 + col;
        bfr[nt] = *(const bf16x8*)((const char*)lB[cur] + row * 128 + (((kc * 4 + g) ^ (row & 7)) << 4));
      }
#pragma unroll
      for (int mt = 0; mt < 2; ++mt)
#pragma unroll
        for (int nt = 0; nt < 2; ++nt)
          acc[mt][nt] = MFMA16(af[mt], bfr[nt], acc[mt][nt]);
    }
    if (s < 3) { CFENCE(); BAR(); }
  }
  float* o = out + (size_t)b * sOut;
#pragma unroll
  for (int mt = 0; mt < 2; ++mt)
#pragma unroll
    for (int r = 0; r < 4; ++r) {
      int row = blockIdx.x * 64 + wr * 32 + mt * 16 + g * 4 + r;
      float bv = bias[row];
#pragma unroll
      for (int nt = 0; nt < 2; ++nt) {
        int cn = blockIdx.y * 64 + wc * 32 + nt * 16 + col;
        o[(size_t)row * 2048 + cn] = acc[mt][nt][r] + bv;
      }
    }
}

// ---------------------------------------------------------------- flash attention
// r13 + ping-pong unroll: even/odd iterations alternate S-register sets, so
// the per-iter 32-VGPR copy (sA=sB) vanishes. One raw barrier per iter,
// counted vmcnt, 4-buffer ring, QK/PV chain-split, exp2-direct softmax.
__global__ __launch_bounds__(256, 2) void k_attn(
    const u16* __restrict__ Qt, const u16* __restrict__ Kt,
    const u16* __restrict__ Vw, u16* __restrict__ Xws)
{
  __shared__ u16 stg[4][2][4096];    // [buf][K|V][64 rows * 64] = 64 KB
  int t = threadIdx.x, l = t & 63;
  int w = t >> 6;
  int hi = l >> 5, col = l & 31;
  int lin = blockIdx.x;
  int xcd = lin & 7, j = lin >> 3;     // j 0..63
  int bh = xcd * 4 + (j >> 4);
  int nb = j & 15;
  int b = bh >> 2, hh = bh & 3;
  const u16* Qb = Qt + ((size_t)(b * 4 + hh) * 2048) * 64;
  const u16* Kb = Kt + ((size_t)(b * 4 + hh) * 2048) * 64;
  const u16* Vb = Vw + ((size_t)(b * 256 + hh * 64)) * 2048;
  int nq = nb * 128 + w * 32 + col;

  bf16x8 qf[4];
#pragma unroll
  for (int ks = 0; ks < 4; ++ks)
    qf[ks] = *(const bf16x8*)&Qb[(size_t)nq * 64 + ks * 16 + hi * 8];

  u32 kSrc[2], vSrc[2], sDst[2];
#pragma unroll
  for (int jj = 0; jj < 2; ++jj) {
    int ci = t + 256 * jj;
    int r = ci >> 3, c = ci & 7;
    u32 sw = (u32)((c ^ ((r >> 1) & 7)) << 4);
    kSrc[jj] = (u32)(r * 128) + sw;
    vSrc[jj] = (u32)(r * 4096) + sw;
    sDst[jj] = (u32)(ci * 16);
  }
  u32 offC[4];
#pragma unroll
  for (int ks = 0; ks < 4; ++ks)
    offC[ks] = (u32)(((2 * ks + hi) ^ ((col >> 1) & 7)) << 4);
  u32 colb = (u32)(col * 128);

  // PV partial accumulators: 4 independent 2-deep chains; merged at epilogue.
  f32x16 xac0a = {}, xac0b = {}, xac1a = {}, xac1b = {};
  float psum = 0.0f, m_run = 0.0f;

  auto stage = [&](int buf, int tile) {
    const char* kb = (const char*)Kb + (size_t)tile * 8192;
    const char* vb = (const char*)Vb + (size_t)tile * 128;
#pragma unroll
    for (int jj = 0; jj < 2; ++jj)
      load_lds16(kb + kSrc[jj], (char*)stg[buf][0] + sDst[jj]);
#pragma unroll
    for (int jj = 0; jj < 2; ++jj)
      load_lds16(vb + vSrc[jj], (char*)stg[buf][1] + sDst[jj]);
  };

  auto ratchet = [&]() {
    if (__any(psum > 16777216.0f)) {
      const float ds = 5.9604644775390625e-8f;   // 2^-24 (never fires for bounded logits)
      xac0a *= ds; xac0b *= ds; xac1a *= ds; xac1b *= ds; psum *= ds;
      m_run += 24.0f;
    }
  };

  // QK: 4 independent 2-deep chains, merged into s0/s1.
  auto do_qk = [&](int buf, f32x16& s0, f32x16& s1) {
    const char* kK = (const char*)stg[buf][0] + colb;
    f32x16 s0a = {}, s0b = {}, s1a = {}, s1b = {};
    __builtin_amdgcn_s_setprio(1);
#pragma unroll
    for (int ks = 0; ks < 2; ++ks) {
      bf16x8 kf0 = *(const bf16x8*)(kK + offC[ks]);
      bf16x8 kf1 = *(const bf16x8*)(kK + 4096 + offC[ks]);
      s0a = MFMA32(kf0, qf[ks], s0a);
      s1a = MFMA32(kf1, qf[ks], s1a);
      bf16x8 kf0b = *(const bf16x8*)(kK + offC[ks + 2]);
      bf16x8 kf1b = *(const bf16x8*)(kK + 4096 + offC[ks + 2]);
      s0b = MFMA32(kf0b, qf[ks + 2], s0b);
      s1b = MFMA32(kf1b, qf[ks + 2], s1b);
    }
    __builtin_amdgcn_s_setprio(0);
    s0 = s0a + s0b;
    s1 = s1a + s1b;
  };

  auto do_sm_pv = [&](int buf, const f32x16& s0, const f32x16& s1) {
    bf16x8 pf[4];
    float ps = 0.0f;
#pragma unroll
    for (int mt = 0; mt < 2; ++mt) {
      const f32x16& sc = mt ? s1 : s0;
      float p[16];
      if (m_run == 0.0f) {                 // wave-uniform fast path (always, in practice)
#pragma unroll
        for (int r = 0; r < 16; ++r) p[r] = __builtin_amdgcn_exp2f(sc[r]);
      } else {
#pragma unroll
        for (int r = 0; r < 16; ++r) p[r] = __builtin_amdgcn_exp2f(sc[r] - m_run);
      }
      ps += ((((p[0] + p[1]) + (p[2] + p[3])) + ((p[4] + p[5]) + (p[6] + p[7])))
          + (((p[8] + p[9]) + (p[10] + p[11])) + ((p[12] + p[13]) + (p[14] + p[15]))));
      u32 A0 = pkbf(p[0],  p[1]),  B0 = pkbf(p[2],  p[3]);
      u32 A1 = pkbf(p[4],  p[5]),  B1 = pkbf(p[6],  p[7]);
      u32 A2 = pkbf(p[8],  p[9]),  B2 = pkbf(p[10], p[11]);
      u32 A3 = pkbf(p[12], p[13]), B3 = pkbf(p[14], p[15]);
      asm("v_permlane32_swap_b32 %0, %1" : "+v"(A0), "+v"(A1));
      asm("v_permlane32_swap_b32 %0, %1" : "+v"(B0), "+v"(B1));
      asm("v_permlane32_swap_b32 %0, %1" : "+v"(A2), "+v"(A3));
      asm("v_permlane32_swap_b32 %0, %1" : "+v"(B2), "+v"(B3));
      union { u32 u[4]; bf16x8 v; } f0, f1;
      f0.u[0] = A0; f0.u[1] = B0; f0.u[2] = A1; f0.u[3] = B1;
      f1.u[0] = A2; f1.u[1] = B2; f1.u[2] = A3; f1.u[3] = B3;
      pf[mt * 2 + 0] = f0.v;
      pf[mt * 2 + 1] = f1.v;
    }
    psum += ps;
    const char* kV = (const char*)stg[buf][1] + colb;
    __builtin_amdgcn_s_setprio(1);
#pragma unroll
    for (int S = 0; S < 2; ++S) {
      bf16x8 vf0 = *(const bf16x8*)(kV + offC[S]);
      bf16x8 vf1 = *(const bf16x8*)(kV + 4096 + offC[S]);
      xac0a = MFMA32(vf0, pf[S], xac0a);
      xac1a = MFMA32(vf1, pf[S], xac1a);
      bf16x8 vf0b = *(const bf16x8*)(kV + offC[S + 2]);
      bf16x8 vf1b = *(const bf16x8*)(kV + 4096 + offC[S + 2]);
      xac0b = MFMA32(vf0b, pf[S + 2], xac0b);
      xac1b = MFMA32(vf1b, pf[S + 2], xac1b);
    }
    __builtin_amdgcn_s_setprio(0);
  };

  // prologue: tiles 0,1 staged; S(0) computed; tile 2 staged
  stage(0, 0);
  stage(1, 1);
  asm volatile("s_waitcnt vmcnt(4)" ::: "memory");
  BAR(); CFENCE();
  f32x16 sA0, sA1, sB0, sB1;
  do_qk(0, sA0, sA1);
  stage(2, 2);

  // 15 ping-pong pairs = iters 0..29 (no S-register copies)
  for (int p = 0; p < 15; ++p) {
    int it = 2 * p;
    // even iter: consume sA(it), produce sB(it+1)
    ratchet();
    asm volatile("s_waitcnt vmcnt(4)" ::: "memory");
    BAR(); CFENCE();
    stage((it + 3) & 3, it + 3);
    do_qk((it + 1) & 3, sB0, sB1);
    do_sm_pv(it & 3, sA0, sA1);
    // odd iter: consume sB(it+1), produce sA(it+2)
    ratchet();
    asm volatile("s_waitcnt vmcnt(4)" ::: "memory");
    BAR(); CFENCE();
    if (it + 4 <= 31) stage((it + 4) & 3, it + 4);
    do_qk((it + 2) & 3, sA0, sA1);
    do_sm_pv((it + 1) & 3, sB0, sB1);
  }
  // iter 30: consume sA(30), produce sB(31)
  ratchet();
  asm volatile("s_waitcnt vmcnt(0)" ::: "memory");
  BAR(); CFENCE();
  do_qk(31 & 3, sB0, sB1);
  do_sm_pv(30 & 3, sA0, sA1);
  // iter 31 tail
  ratchet();
  do_sm_pv(31 & 3, sB0, sB1);

  f32x16 xac0 = xac0a + xac0b;
  f32x16 xac1 = xac1a + xac1b;
  psum += __shfl_xor(psum, 32);
  float inv = 1.0f / psum;
  u16* Ob = Xws + (size_t)b * 2048 * 256 + (size_t)nq * 256 + hh * 64;
#pragma unroll
  for (int it2 = 0; it2 < 2; ++it2) {
    const f32x16& xa = it2 ? xac1 : xac0;
#pragma unroll
    for (int rq = 0; rq < 4; ++rq) {
      float v0 = xa[4 * rq + 0] * inv;
      float v1 = xa[4 * rq + 1] * inv;
      float v2 = xa[4 * rq + 2] * inv;
      float v3 = xa[4 * rq + 3] * inv;
      u32x2 w2; w2[0] = pkbf(v0, v1); w2[1] = pkbf(v2, v3);
      *(u32x2*)&Ob[it2 * 32 + 8 * rq + 4 * hi] = w2;
    }
  }
}

// ---------------------------------------------------------------- launch
extern "C" void kernel_launch(void* const* d_in, const int* in_sizes, int n_in,
                              void* d_out, int out_size, void* d_ws, size_t ws_size,
                              hipStream_t stream)
{
  const float* q_in = (const float*)d_in[0];
  const float* k_in = (const float*)d_in[1];
  const float* v_in = (const float*)d_in[2];
  const float* w_q  = (const float*)d_in[3];
  const float* b_q  = (const float*)d_in[4];
  const float* w_k  = (const float*)d_in[5];
  const float* b_k  = (const float*)d_in[6];
  const float* w_v  = (const float*)d_in[7];
  const float* b_v  = (const float*)d_in[8];
  const float* w_m  = (const float*)d_in[9];
  const float* b_m  = (const float*)d_in[10];

  char* ws = (char*)d_ws;
  u16* XT_Q = (u16*)(ws + 0);           // [8][2048][256] bf16; reused as attn out
  u16* XT_K = (u16*)(ws + 8388608);
  u16* XT_V = (u16*)(ws + 16777216);
  u16* QT   = (u16*)(ws + 25165824);    // [8][4][2048][64]
  u16* KT   = (u16*)(ws + 33554432);
  u16* VW   = (u16*)(ws + 41943040);    // [8][256][2048]
  u16* WQ   = (u16*)(ws + 50331648);
  u16* WK   = (u16*)(ws + 50462720);
  u16* WV   = (u16*)(ws + 50593792);
  u16* WM   = (u16*)(ws + 50724864);
  float* BQ = (float*)(ws + 50855936);
  float* BK = (float*)(ws + 50856960);
  float* BV = (float*)(ws + 50857984);

  k_pre<<<dim3(4352), 256, 0, stream>>>(q_in, k_in, v_in, w_q, w_k, w_v, w_m,
                                        b_q, b_k, b_v, XT_Q, XT_K, XT_V,
                                        WQ, WK, WV, WM, BQ, BK, BV);
  k_gemm3<<<dim3(3072), 256, 0, stream>>>(XT_Q, XT_K, XT_V, WQ, WK, WV,
                                          BQ, BK, BV, QT, KT, VW);
  k_attn<<<dim3(512), 256, 0, stream>>>(QT, KT, VW, XT_Q);
  k_gemmM<<<dim3(4, 32, 8), 256, 0, stream>>>(WM, XT_Q, 2048L * 256, b_m,
                                              (float*)d_out, 256L * 2048);
}

// Round 15
// 93.365 us; speedup vs baseline: 1.0549x; 1.0549x over previous
//
#include <hip/hip_runtime.h>
#include <cstdint>
#include <cstddef>

typedef unsigned short u16;
typedef unsigned int   u32;
typedef __attribute__((ext_vector_type(4))) float f32x4;
typedef __attribute__((ext_vector_type(16))) float f32x16;
typedef __attribute__((ext_vector_type(8))) short bf16x8;
typedef __attribute__((ext_vector_type(2))) u32 u32x2;
typedef __attribute__((ext_vector_type(4))) u32 u32x4;

#define DEVI static __device__ __forceinline__
#define MFMA16(a,b,c) __builtin_amdgcn_mfma_f32_16x16x32_bf16((a),(b),(c),0,0,0)
#define MFMA32(a,b,c) __builtin_amdgcn_mfma_f32_32x32x16_bf16((a),(b),(c),0,0,0)
#define BAR()   __builtin_amdgcn_s_barrier()
#define CFENCE() asm volatile("" ::: "memory")

DEVI u16 f2b(float f) {
  u32 u = __builtin_bit_cast(u32, f);
  u32 r = u + 0x7fffu + ((u >> 16) & 1u);
  return (u16)(r >> 16);
}

DEVI u32 pkbf(float a, float b) {
  u32 r;
  asm("v_cvt_pk_bf16_f32 %0, %1, %2" : "=v"(r) : "v"(a), "v"(b));
  return r;
}

DEVI void load_lds16(const void* g, void* l) {
  __builtin_amdgcn_global_load_lds(
      (const __attribute__((address_space(1))) u32*)g,
      (__attribute__((address_space(3))) u32*)l, 16, 0, 0);
}

DEVI int perm_o(int o) { return 4 * (o & 63) + (o >> 6); }   // o' = h*64+i -> o = 4i+h

// ------------------------------------------------ merged: transpose(3072 blks) + weight prep(1280)
__global__ __launch_bounds__(256) void k_pre(
    const float* __restrict__ q, const float* __restrict__ k, const float* __restrict__ v,
    const float* __restrict__ wq, const float* __restrict__ wk,
    const float* __restrict__ wv, const float* __restrict__ wm,
    const float* __restrict__ bq, const float* __restrict__ bk, const float* __restrict__ bv,
    u16* __restrict__ xq, u16* __restrict__ xk, u16* __restrict__ xv,
    u16* __restrict__ WQ, u16* __restrict__ WK, u16* __restrict__ WV, u16* __restrict__ WM,
    float* __restrict__ BQ, float* __restrict__ BK, float* __restrict__ BV)
{
  __shared__ u16 tile[64][68];
  int blk = blockIdx.x, t = threadIdx.x;
  if (blk < 3072) {
    const int N = 2048, D = 256;
    int x = blk & 31, y = (blk >> 5) & 3, z = blk >> 7;
    int n0 = x * 64, c0 = y * 64;
    int b = z & 7, which = z >> 3;
    const float* src = (which == 0 ? q : which == 1 ? k : v) + (size_t)b * D * N;
    u16* dst = (which == 0 ? xq : which == 1 ? xk : xv) + (size_t)b * N * D;
    int cl = t >> 4, ng = t & 15;
#pragma unroll
    for (int cc = 0; cc < 4; ++cc) {
      int c = cl + 16 * cc;
      f32x4 val = *(const f32x4*)&src[(size_t)(c0 + c) * N + n0 + ng * 4];
#pragma unroll
      for (int j = 0; j < 4; ++j) tile[c][ng * 4 + j] = f2b(val[j]);
    }
    __syncthreads();
    int n = t & 63, cq = t >> 6;
    union { u16 s[16]; u32x4 v4[2]; } pk;
#pragma unroll
    for (int j = 0; j < 16; ++j) pk.s[j] = tile[cq * 16 + j][n];
    u32x4* o = (u32x4*)&dst[(size_t)(n0 + n) * D + c0 + cq * 16];
    o[0] = pk.v4[0];
    o[1] = pk.v4[1];
  } else {
    int p = blk - 3072;
    int row = p & 255, m = p >> 8;
    if (m == 0)      WQ[row * 256 + t] = f2b(wq[perm_o(row) * 256 + t]);
    else if (m == 1) WK[row * 256 + t] = f2b(wk[perm_o(row) * 256 + t]);
    else if (m == 2) WV[row * 256 + t] = f2b(wv[perm_o(row) * 256 + t]);
    else if (m == 3) WM[row * 256 + t] = f2b(wm[row * 256 + perm_o(t)]);
    else if (row == 0) {
      BQ[t] = bq[perm_o(t)];
      BK[t] = bk[perm_o(t)];
      BV[t] = bv[perm_o(t)];
    }
  }
}

// ------------------------------------------------ merged Q/K/V projection GEMM
// 128x128 tile, BK=64 (m93/m97-proven shape): 4 waves, each 4x4 16x16 frags.
// Single-buffered LDS (32KB) -> 3 blocks/CU, grid 768 = ALL resident (no tail).
// Q output PRE-SCALED by SC2 = 0.125*log2(e).
__global__ __launch_bounds__(256, 3) void k_gemm3(
    const u16* __restrict__ XQ, const u16* __restrict__ XK, const u16* __restrict__ XV,
    const u16* __restrict__ WQm, const u16* __restrict__ WKm, const u16* __restrict__ WVm,
    const float* __restrict__ BQ, const float* __restrict__ BK, const float* __restrict__ BV,
    u16* __restrict__ QT, u16* __restrict__ KT, u16* __restrict__ VW)
{
  __shared__ u16 lA[128 * 64];
  __shared__ u16 lB[128 * 64];
  int gid = blockIdx.x, t = threadIdx.x;
  int b, bx, by, epi;
  const u16 *Ab, *Bb;
  const float* bias;
  u16* outp;
  float osc = 1.0f;
  if (gid < 512) {
    int wk = gid >> 8;                    // 0=Q 1=K
    int rem = gid & 255;
    b  = rem >> 5;
    bx = (rem >> 1) & 15;                 // M tile (2048/128)
    by = rem & 1;                         // N tile (256/128), fastest: A-panel L2 reuse
    Ab = (wk ? XK : XQ) + (size_t)b * (2048 * 256) + (size_t)bx * 128 * 256;
    Bb = (wk ? WKm : WQm) + (size_t)by * 128 * 256;
    bias = wk ? BK : BQ;
    outp = (wk ? KT : QT) + (size_t)b * (4L * 2048 * 64);
    epi = 0;
    if (wk == 0) osc = 0.18033688011112042f;
  } else {
    int g2 = gid - 512;
    b  = g2 >> 5;
    by = (g2 >> 1) & 15;                  // N tile (2048/128)
    bx = g2 & 1;                          // M tile (256/128), fastest
    Ab = WVm + (size_t)bx * 128 * 256;
    Bb = XV + (size_t)b * (2048 * 256) + (size_t)by * 128 * 256;
    bias = BV;
    outp = VW + (size_t)b * (256L * 2048);
    epi = 1;
  }
  int l = t & 63, w = t >> 6, g = l >> 4, col = l & 15;
  int wr = w >> 1, wc = w & 1;
  f32x4 acc[4][4] = {};
  u32 sOf[4], sDs[4];
#pragma unroll
  for (int j = 0; j < 4; ++j) {
    int ci = t + 256 * j;                 // 0..1023 chunks (128 rows x 8)
    int r = ci >> 3, c = ci & 7;
    sOf[j] = (u32)(r * 512 + ((c ^ (r & 7)) << 4));
    sDs[j] = (u32)(ci * 16);
  }
  for (int s = 0; s < 4; ++s) {
    if (s) { CFENCE(); BAR(); }           // prev compute done reading LDS
#pragma unroll
    for (int j = 0; j < 4; ++j)
      load_lds16((const char*)Ab + s * 128 + sOf[j], (char*)lA + sDs[j]);
#pragma unroll
    for (int j = 0; j < 4; ++j)
      load_lds16((const char*)Bb + s * 128 + sOf[j], (char*)lB + sDs[j]);
    asm volatile("s_waitcnt vmcnt(0)" ::: "memory");
    BAR(); CFENCE();
#pragma unroll
    for (int kc = 0; kc < 2; ++kc) {
      bf16x8 af[4], bfr[4];
#pragma unroll
      for (int mt = 0; mt < 4; ++mt) {
        int row = wr * 64 + mt * 16 + col;
        af[mt] = *(const bf16x8*)((const char*)lA + row * 128 + (((kc * 4 + g) ^ (row & 7)) << 4));
      }
#pragma unroll
      for (int nt = 0; nt < 4; ++nt) {
        int row = wc * 64 + nt * 16 + col;
        bfr[nt] = *(const bf16x8*)((const char*)lB + row * 128 + (((kc * 4 + g) ^ (row & 7)) << 4));
      }
#pragma unroll
      for (int mt = 0; mt < 4; ++mt)
#pragma unroll
        for (int nt = 0; nt < 4; ++nt)
          acc[mt][nt] = MFMA16(af[mt], bfr[nt], acc[mt][nt]);
    }
  }
  if (epi == 0) {
#pragma unroll
    for (int nt = 0; nt < 4; ++nt) {
      int op = by * 128 + wc * 64 + nt * 16 + col;
      int hh = op >> 6, ii = op & 63;
      float bv = bias[op];
#pragma unroll
      for (int mt = 0; mt < 4; ++mt) {
        int nbase = bx * 128 + wr * 64 + mt * 16 + g * 4;
#pragma unroll
        for (int r = 0; r < 4; ++r)
          outp[((size_t)(hh * 2048 + nbase + r)) * 64 + ii] = f2b((acc[mt][nt][r] + bv) * osc);
      }
    }
  } else {
#pragma unroll
    for (int mt = 0; mt < 4; ++mt)
#pragma unroll
      for (int r = 0; r < 4; ++r) {
        int row = bx * 128 + wr * 64 + mt * 16 + g * 4 + r;
        float bv = bias[row];
#pragma unroll
        for (int nt = 0; nt < 4; ++nt) {
          int cn = by * 128 + wc * 64 + nt * 16 + col;
          outp[(size_t)row * 2048 + cn] = f2b(acc[mt][nt][r] + bv);
        }
      }
  }
}

// ---------------------------------------------------------------- final M-proj GEMM (f32 out)
__global__ __launch_bounds__(256, 4) void k_gemmM(
    const u16* __restrict__ A,
    const u16* __restrict__ Bm, long sB,
    const float* __restrict__ bias,
    float* __restrict__ out, long sOut)
{
  __shared__ u16 lA[2][64 * 64];
  __shared__ u16 lB[2][64 * 64];
  int t = threadIdx.x, b = blockIdx.z;
  const u16* Ab = A + (size_t)blockIdx.x * 64 * 256;
  const u16* Bb = Bm + (size_t)b * sB + (size_t)blockIdx.y * 64 * 256;
  int l = t & 63, w = t >> 6, g = l >> 4, col = l & 15;
  int wr = w >> 1, wc = w & 1;
  f32x4 acc[2][2] = {};
  u32 sOf[2], sDs[2];
#pragma unroll
  for (int j = 0; j < 2; ++j) {
    int ci = t + 256 * j;
    int r = ci >> 3, c = ci & 7;
    sOf[j] = (u32)(r * 512 + ((c ^ (r & 7)) << 4));
    sDs[j] = (u32)(ci * 16);
  }
  auto stage = [&](int buf, int k0) {
#pragma unroll
    for (int j = 0; j < 2; ++j) {
      load_lds16((const char*)Ab + k0 * 2 + sOf[j], (char*)lA[buf] + sDs[j]);
      load_lds16((const char*)Bb + k0 * 2 + sOf[j], (char*)lB[buf] + sDs[j]);
    }
  };
  stage(0, 0);
  for (int s = 0; s < 4; ++s) {
    int cur = s & 1;
    if (s < 3) {
      stage(cur ^ 1, (s + 1) * 64);
      asm volatile("s_waitcnt vmcnt(4)" ::: "memory");
    } else {
      asm volatile("s_waitcnt vmcnt(0)" ::: "memory");
    }
    BAR(); CFENCE();
#pragma unroll
    for (int kc = 0; kc < 2; ++kc) {
      bf16x8 af[2], bfr[2];
#pragma unroll
      for (int mt = 0; mt < 2; ++mt) {
        int row = wr * 32 + mt * 16 + col;
        af[mt] = *(const bf16x8*)((const char*)lA[cur] + row * 128 + (((kc * 4 + g) ^ (row & 7)) << 4));
      }
#pragma unroll
      for (int nt = 0; nt < 2; ++nt) {
        int row = wc * 32 + nt * 16 + col;
        bfr[nt] = *(const bf16x8*)((const char*)lB[cur] + row * 128 + (((kc * 4 + g) ^ (row & 7)) << 4));
      }
#pragma unroll
      for (int mt = 0; mt < 2; ++mt)
#pragma unroll
        for (int nt = 0; nt < 2; ++nt)
          acc[mt][nt] = MFMA16(af[mt], bfr[nt], acc[mt][nt]);
    }
    if (s < 3) { CFENCE(); BAR(); }
  }
  float* o = out + (size_t)b * sOut;
#pragma unroll
  for (int mt = 0; mt < 2; ++mt)
#pragma unroll
    for (int r = 0; r < 4; ++r) {
      int row = blockIdx.x * 64 + wr * 32 + mt * 16 + g * 4 + r;
      float bv = bias[row];
#pragma unroll
      for (int nt = 0; nt < 2; ++nt) {
        int cn = blockIdx.y * 64 + wc * 32 + nt * 16 + col;
        o[(size_t)row * 2048 + cn] = acc[mt][nt][r] + bv;
      }
    }
}

// ---------------------------------------------------------------- flash attention (r13 champion)
// 4 waves x 32 q-rows, grid 512 XCD-swizzled, 4-buffer ring 64KB, counted
// vmcnt, one raw barrier/iter, QK/PV chain-split, exp2-direct softmax.
__global__ __launch_bounds__(256, 2) void k_attn(
    const u16* __restrict__ Qt, const u16* __restrict__ Kt,
    const u16* __restrict__ Vw, u16* __restrict__ Xws)
{
  __shared__ u16 stg[4][2][4096];    // [buf][K|V][64 rows * 64] = 64 KB
  int t = threadIdx.x, l = t & 63;
  int w = t >> 6;
  int hi = l >> 5, col = l & 31;
  int lin = blockIdx.x;
  int xcd = lin & 7, j = lin >> 3;     // j 0..63
  int bh = xcd * 4 + (j >> 4);
  int nb = j & 15;
  int b = bh >> 2, hh = bh & 3;
  const u16* Qb = Qt + ((size_t)(b * 4 + hh) * 2048) * 64;
  const u16* Kb = Kt + ((size_t)(b * 4 + hh) * 2048) * 64;
  const u16* Vb = Vw + ((size_t)(b * 256 + hh * 64)) * 2048;
  int nq = nb * 128 + w * 32 + col;

  bf16x8 qf[4];
#pragma unroll
  for (int ks = 0; ks < 4; ++ks)
    qf[ks] = *(const bf16x8*)&Qb[(size_t)nq * 64 + ks * 16 + hi * 8];

  u32 kSrc[2], vSrc[2], sDst[2];
#pragma unroll
  for (int jj = 0; jj < 2; ++jj) {
    int ci = t + 256 * jj;
    int r = ci >> 3, c = ci & 7;
    u32 sw = (u32)((c ^ ((r >> 1) & 7)) << 4);
    kSrc[jj] = (u32)(r * 128) + sw;
    vSrc[jj] = (u32)(r * 4096) + sw;
    sDst[jj] = (u32)(ci * 16);
  }
  u32 offC[4];
#pragma unroll
  for (int ks = 0; ks < 4; ++ks)
    offC[ks] = (u32)(((2 * ks + hi) ^ ((col >> 1) & 7)) << 4);
  u32 colb = (u32)(col * 128);

  // PV partial accumulators: 4 independent 2-deep chains; merged at epilogue.
  f32x16 xac0a = {}, xac0b = {}, xac1a = {}, xac1b = {};
  float psum = 0.0f, m_run = 0.0f;

  auto stage = [&](int buf, int tile) {
    const char* kb = (const char*)Kb + (size_t)tile * 8192;
    const char* vb = (const char*)Vb + (size_t)tile * 128;
#pragma unroll
    for (int jj = 0; jj < 2; ++jj)
      load_lds16(kb + kSrc[jj], (char*)stg[buf][0] + sDst[jj]);
#pragma unroll
    for (int jj = 0; jj < 2; ++jj)
      load_lds16(vb + vSrc[jj], (char*)stg[buf][1] + sDst[jj]);
  };

  // QK: 4 independent 2-deep chains (s0a,s0b,s1a,s1b), merged by caller.
  auto do_qk = [&](int buf, f32x16& s0, f32x16& s1) {
    const char* kK = (const char*)stg[buf][0] + colb;
    f32x16 s0a = {}, s0b = {}, s1a = {}, s1b = {};
    __builtin_amdgcn_s_setprio(1);
#pragma unroll
    for (int ks = 0; ks < 2; ++ks) {
      bf16x8 kf0 = *(const bf16x8*)(kK + offC[ks]);
      bf16x8 kf1 = *(const bf16x8*)(kK + 4096 + offC[ks]);
      s0a = MFMA32(kf0, qf[ks], s0a);
      s1a = MFMA32(kf1, qf[ks], s1a);
      bf16x8 kf0b = *(const bf16x8*)(kK + offC[ks + 2]);
      bf16x8 kf1b = *(const bf16x8*)(kK + 4096 + offC[ks + 2]);
      s0b = MFMA32(kf0b, qf[ks + 2], s0b);
      s1b = MFMA32(kf1b, qf[ks + 2], s1b);
    }
    __builtin_amdgcn_s_setprio(0);
    s0 = s0a + s0b;
    s1 = s1a + s1b;
  };

  auto do_sm_pv = [&](int buf, const f32x16& s0, const f32x16& s1) {
    bf16x8 pf[4];
    float ps = 0.0f;
#pragma unroll
    for (int mt = 0; mt < 2; ++mt) {
      const f32x16& sc = mt ? s1 : s0;
      float p[16];
      if (m_run == 0.0f) {                 // wave-uniform fast path (always, in practice)
#pragma unroll
        for (int r = 0; r < 16; ++r) p[r] = __builtin_amdgcn_exp2f(sc[r]);
      } else {
#pragma unroll
        for (int r = 0; r < 16; ++r) p[r] = __builtin_amdgcn_exp2f(sc[r] - m_run);
      }
      ps += ((((p[0] + p[1]) + (p[2] + p[3])) + ((p[4] + p[5]) + (p[6] + p[7])))
          + (((p[8] + p[9]) + (p[10] + p[11])) + ((p[12] + p[13]) + (p[14] + p[15]))));
      u32 A0 = pkbf(p[0],  p[1]),  B0 = pkbf(p[2],  p[3]);
      u32 A1 = pkbf(p[4],  p[5]),  B1 = pkbf(p[6],  p[7]);
      u32 A2 = pkbf(p[8],  p[9]),  B2 = pkbf(p[10], p[11]);
      u32 A3 = pkbf(p[12], p[13]), B3 = pkbf(p[14], p[15]);
      asm("v_permlane32_swap_b32 %0, %1" : "+v"(A0), "+v"(A1));
      asm("v_permlane32_swap_b32 %0, %1" : "+v"(B0), "+v"(B1));
      asm("v_permlane32_swap_b32 %0, %1" : "+v"(A2), "+v"(A3));
      asm("v_permlane32_swap_b32 %0, %1" : "+v"(B2), "+v"(B3));
      union { u32 u[4]; bf16x8 v; } f0, f1;
      f0.u[0] = A0; f0.u[1] = B0; f0.u[2] = A1; f0.u[3] = B1;
      f1.u[0] = A2; f1.u[1] = B2; f1.u[2] = A3; f1.u[3] = B3;
      pf[mt * 2 + 0] = f0.v;
      pf[mt * 2 + 1] = f1.v;
    }
    psum += ps;
    const char* kV = (const char*)stg[buf][1] + colb;
    // PV: 4 independent 2-deep chains (a: S=0,1; b: S=2,3)
    __builtin_amdgcn_s_setprio(1);
#pragma unroll
    for (int S = 0; S < 2; ++S) {
      bf16x8 vf0 = *(const bf16x8*)(kV + offC[S]);
      bf16x8 vf1 = *(const bf16x8*)(kV + 4096 + offC[S]);
      xac0a = MFMA32(vf0, pf[S], xac0a);
      xac1a = MFMA32(vf1, pf[S], xac1a);
      bf16x8 vf0b = *(const bf16x8*)(kV + offC[S + 2]);
      bf16x8 vf1b = *(const bf16x8*)(kV + 4096 + offC[S + 2]);
      xac0b = MFMA32(vf0b, pf[S + 2], xac0b);
      xac1b = MFMA32(vf1b, pf[S + 2], xac1b);
    }
    __builtin_amdgcn_s_setprio(0);
  };

  // prologue: tiles 0,1 staged; S(0) computed; tile 2 staged
  stage(0, 0);
  stage(1, 1);
  asm volatile("s_waitcnt vmcnt(4)" ::: "memory");
  BAR(); CFENCE();
  f32x16 sA0, sA1;
  do_qk(0, sA0, sA1);
  stage(2, 2);

  for (int it = 0; it < 31; ++it) {
    // ratchet rescale (never fires for bounded logits; correctness fallback)
    if (__any(psum > 16777216.0f)) {
      const float ds = 5.9604644775390625e-8f;   // 2^-24
      xac0a *= ds; xac0b *= ds; xac1a *= ds; xac1b *= ds; psum *= ds;
      m_run += 24.0f;
    }
    if (it < 30) {
      asm volatile("s_waitcnt vmcnt(4)" ::: "memory");   // tile it+1 landed
    } else {
      asm volatile("s_waitcnt vmcnt(0)" ::: "memory");   // tile 31 landed
    }
    BAR(); CFENCE();                                     // single barrier per iter
    if (it + 3 <= 31) stage((it + 3) & 3, it + 3);       // overwrites buf[it-1] (freed by BAR)
    f32x16 sB0, sB1;
    do_qk((it + 1) & 3, sB0, sB1);                       // MFMA, independent of softmax(it)
    do_sm_pv(it & 3, sA0, sA1);                          // VALU + MFMA
    sA0 = sB0; sA1 = sB1;
  }
  if (__any(psum > 16777216.0f)) {
    const float ds = 5.9604644775390625e-8f;
    xac0a *= ds; xac0b *= ds; xac1a *= ds; xac1b *= ds; psum *= ds;
    m_run += 24.0f;
  }
  do_sm_pv(31 & 3, sA0, sA1);

  f32x16 xac0 = xac0a + xac0b;
  f32x16 xac1 = xac1a + xac1b;
  psum += __shfl_xor(psum, 32);
  float inv = 1.0f / psum;
  u16* Ob = Xws + (size_t)b * 2048 * 256 + (size_t)nq * 256 + hh * 64;
#pragma unroll
  for (int it2 = 0; it2 < 2; ++it2) {
    const f32x16& xa = it2 ? xac1 : xac0;
#pragma unroll
    for (int rq = 0; rq < 4; ++rq) {
      float v0 = xa[4 * rq + 0] * inv;
      float v1 = xa[4 * rq + 1] * inv;
      float v2 = xa[4 * rq + 2] * inv;
      float v3 = xa[4 * rq + 3] * inv;
      u32x2 w2; w2[0] = pkbf(v0, v1); w2[1] = pkbf(v2, v3);
      *(u32x2*)&Ob[it2 * 32 + 8 * rq + 4 * hi] = w2;
    }
  }
}

// ---------------------------------------------------------------- launch
extern "C" void kernel_launch(void* const* d_in, const int* in_sizes, int n_in,
                              void* d_out, int out_size, void* d_ws, size_t ws_size,
                              hipStream_t stream)
{
  const float* q_in = (const float*)d_in[0];
  const float* k_in = (const float*)d_in[1];
  const float* v_in = (const float*)d_in[2];
  const float* w_q  = (const float*)d_in[3];
  const float* b_q  = (const float*)d_in[4];
  const float* w_k  = (const float*)d_in[5];
  const float* b_k  = (const float*)d_in[6];
  const float* w_v  = (const float*)d_in[7];
  const float* b_v  = (const float*)d_in[8];
  const float* w_m  = (const float*)d_in[9];
  const float* b_m  = (const float*)d_in[10];

  char* ws = (char*)d_ws;
  u16* XT_Q = (u16*)(ws + 0);           // [8][2048][256] bf16; reused as attn out
  u16* XT_K = (u16*)(ws + 8388608);
  u16* XT_V = (u16*)(ws + 16777216);
  u16* QT   = (u16*)(ws + 25165824);    // [8][4][2048][64]
  u16* KT   = (u16*)(ws + 33554432);
  u16* VW   = (u16*)(ws + 41943040);    // [8][256][2048]
  u16* WQ   = (u16*)(ws + 50331648);
  u16* WK   = (u16*)(ws + 50462720);
  u16* WV   = (u16*)(ws + 50593792);
  u16* WM   = (u16*)(ws + 50724864);
  float* BQ = (float*)(ws + 50855936);
  float* BK = (float*)(ws + 50856960);
  float* BV = (float*)(ws + 50857984);

  k_pre<<<dim3(4352), 256, 0, stream>>>(q_in, k_in, v_in, w_q, w_k, w_v, w_m,
                                        b_q, b_k, b_v, XT_Q, XT_K, XT_V,
                                        WQ, WK, WV, WM, BQ, BK, BV);
  k_gemm3<<<dim3(768), 256, 0, stream>>>(XT_Q, XT_K, XT_V, WQ, WK, WV,
                                         BQ, BK, BV, QT, KT, VW);
  k_attn<<<dim3(512), 256, 0, stream>>>(QT, KT, VW, XT_Q);
  k_gemmM<<<dim3(4, 32, 8), 256, 0, stream>>>(WM, XT_Q, 2048L * 256, b_m,
                                              (float*)d_out, 256L * 2048);
}

// Round 16
// 93.085 us; speedup vs baseline: 1.0581x; 1.0030x over previous
//
#include <hip/hip_runtime.h>
#include <cstdint>
#include <cstddef>

typedef unsigned short u16;
typedef unsigned int   u32;
typedef __attribute__((ext_vector_type(2))) float f32x2;
typedef __attribute__((ext_vector_type(4))) float f32x4;
typedef __attribute__((ext_vector_type(16))) float f32x16;
typedef __attribute__((ext_vector_type(8))) short bf16x8;
typedef __attribute__((ext_vector_type(2))) u32 u32x2;
typedef __attribute__((ext_vector_type(4))) u32 u32x4;

#define DEVI static __device__ __forceinline__
#define MFMA16(a,b,c) __builtin_amdgcn_mfma_f32_16x16x32_bf16((a),(b),(c),0,0,0)
#define MFMA32(a,b,c) __builtin_amdgcn_mfma_f32_32x32x16_bf16((a),(b),(c),0,0,0)
#define BAR()   __builtin_amdgcn_s_barrier()
#define CFENCE() asm volatile("" ::: "memory")

DEVI u16 f2b(float f) {
  u32 u = __builtin_bit_cast(u32, f);
  u32 r = u + 0x7fffu + ((u >> 16) & 1u);
  return (u16)(r >> 16);
}

DEVI u32 pkbf(float a, float b) {
  u32 r;
  asm("v_cvt_pk_bf16_f32 %0, %1, %2" : "=v"(r) : "v"(a), "v"(b));
  return r;
}

DEVI void load_lds16(const void* g, void* l) {
  __builtin_amdgcn_global_load_lds(
      (const __attribute__((address_space(1))) u32*)g,
      (__attribute__((address_space(3))) u32*)l, 16, 0, 0);
}

DEVI int perm_o(int o) { return 4 * (o & 63) + (o >> 6); }   // o' = h*64+i -> o = 4i+h

// ------------------------------------------------ merged: transpose(3072 blks) + weight prep(1280)
// Transpose: 64n x 64c tile stored in LDS as [n][c] bf16 with 16B-chunk XOR
// swizzle (chunk ^= n&7). Phase1: 8x f32x2 loads -> 8 cvt_pk -> 2 ds_write_b128.
// Phase2: 2 ds_read_b128 (2-way max) -> 2x 16B global stores.
__global__ __launch_bounds__(256) void k_pre(
    const float* __restrict__ q, const float* __restrict__ k, const float* __restrict__ v,
    const float* __restrict__ wq, const float* __restrict__ wk,
    const float* __restrict__ wv, const float* __restrict__ wm,
    const float* __restrict__ bq, const float* __restrict__ bk, const float* __restrict__ bv,
    u16* __restrict__ xq, u16* __restrict__ xk, u16* __restrict__ xv,
    u16* __restrict__ WQ, u16* __restrict__ WK, u16* __restrict__ WV, u16* __restrict__ WM,
    float* __restrict__ BQ, float* __restrict__ BK, float* __restrict__ BV)
{
  __shared__ u16 tileT[64 * 64];   // [n][c], chunk-swizzled
  int blk = blockIdx.x, t = threadIdx.x;
  if (blk < 3072) {
    const int N = 2048, D = 256;
    int x = blk & 31, y = (blk >> 5) & 3, z = blk >> 7;
    int n0b = x * 64, c0b = y * 64;
    int b = z & 7, which = z >> 3;
    const float* src = (which == 0 ? q : which == 1 ? k : v) + (size_t)b * D * N;
    u16* dst = (which == 0 ? xq : which == 1 ? xk : xv) + (size_t)b * N * D;
    // phase 1: thread covers c-block 8cg..8cg+7, n = 2*ng2, 2*ng2+1
    int cg = t >> 5, ng2 = t & 31;
    f32x2 la[8];
#pragma unroll
    for (int j = 0; j < 8; ++j)
      la[j] = *(const f32x2*)&src[(size_t)(c0b + cg * 8 + j) * N + n0b + ng2 * 2];
#pragma unroll
    for (int jn = 0; jn < 2; ++jn) {
      int ln = ng2 * 2 + jn;
      u32x4 W;
#pragma unroll
      for (int qd = 0; qd < 4; ++qd)
        W[qd] = pkbf(la[2 * qd][jn], la[2 * qd + 1][jn]);
      *(u32x4*)((char*)tileT + ln * 128 + ((cg ^ (ln & 7)) << 4)) = W;
    }
    __syncthreads();
    // phase 2: thread (n = t&63, cq = t>>6) reads chunks 2cq, 2cq+1 of row n
    int ln = t & 63, cq = t >> 6;
    u32x4 a0 = *(const u32x4*)((const char*)tileT + ln * 128 + (((2 * cq + 0) ^ (ln & 7)) << 4));
    u32x4 a1 = *(const u32x4*)((const char*)tileT + ln * 128 + (((2 * cq + 1) ^ (ln & 7)) << 4));
    u16* dp = &dst[(size_t)(n0b + ln) * D + c0b + cq * 16];
    *(u32x4*)dp = a0;
    *(u32x4*)(dp + 8) = a1;
  } else {
    int p = blk - 3072;
    int row = p & 255, m = p >> 8;
    if (m == 0)      WQ[row * 256 + t] = f2b(wq[perm_o(row) * 256 + t]);
    else if (m == 1) WK[row * 256 + t] = f2b(wk[perm_o(row) * 256 + t]);
    else if (m == 2) WV[row * 256 + t] = f2b(wv[perm_o(row) * 256 + t]);
    else if (m == 3) WM[row * 256 + t] = f2b(wm[row * 256 + perm_o(t)]);
    else if (row == 0) {
      BQ[t] = bq[perm_o(t)];
      BK[t] = bk[perm_o(t)];
      BV[t] = bv[perm_o(t)];
    }
  }
}

// ------------------------------------------------ merged Q/K/V projection GEMM
// 128x128 tile, BK=64: 4 waves, each 4x4 16x16 frags. Single-buffered LDS
// (32KB) -> 3 blocks/CU, grid 768 all-resident. Q PRE-SCALED by SC2.
__global__ __launch_bounds__(256, 3) void k_gemm3(
    const u16* __restrict__ XQ, const u16* __restrict__ XK, const u16* __restrict__ XV,
    const u16* __restrict__ WQm, const u16* __restrict__ WKm, const u16* __restrict__ WVm,
    const float* __restrict__ BQ, const float* __restrict__ BK, const float* __restrict__ BV,
    u16* __restrict__ QT, u16* __restrict__ KT, u16* __restrict__ VW)
{
  __shared__ u16 lA[128 * 64];
  __shared__ u16 lB[128 * 64];
  int gid = blockIdx.x, t = threadIdx.x;
  int b, bx, by, epi;
  const u16 *Ab, *Bb;
  const float* bias;
  u16* outp;
  float osc = 1.0f;
  if (gid < 512) {
    int wk = gid >> 8;                    // 0=Q 1=K
    int rem = gid & 255;
    b  = rem >> 5;
    bx = (rem >> 1) & 15;                 // M tile (2048/128)
    by = rem & 1;                         // N tile fastest: A-panel L2 reuse
    Ab = (wk ? XK : XQ) + (size_t)b * (2048 * 256) + (size_t)bx * 128 * 256;
    Bb = (wk ? WKm : WQm) + (size_t)by * 128 * 256;
    bias = wk ? BK : BQ;
    outp = (wk ? KT : QT) + (size_t)b * (4L * 2048 * 64);
    epi = 0;
    if (wk == 0) osc = 0.18033688011112042f;
  } else {
    int g2 = gid - 512;
    b  = g2 >> 5;
    by = (g2 >> 1) & 15;
    bx = g2 & 1;
    Ab = WVm + (size_t)bx * 128 * 256;
    Bb = XV + (size_t)b * (2048 * 256) + (size_t)by * 128 * 256;
    bias = BV;
    outp = VW + (size_t)b * (256L * 2048);
    epi = 1;
  }
  int l = t & 63, w = t >> 6, g = l >> 4, col = l & 15;
  int wr = w >> 1, wc = w & 1;
  f32x4 acc[4][4] = {};
  u32 sOf[4], sDs[4];
#pragma unroll
  for (int j = 0; j < 4; ++j) {
    int ci = t + 256 * j;
    int r = ci >> 3, c = ci & 7;
    sOf[j] = (u32)(r * 512 + ((c ^ (r & 7)) << 4));
    sDs[j] = (u32)(ci * 16);
  }
  for (int s = 0; s < 4; ++s) {
    if (s) { CFENCE(); BAR(); }
#pragma unroll
    for (int j = 0; j < 4; ++j)
      load_lds16((const char*)Ab + s * 128 + sOf[j], (char*)lA + sDs[j]);
#pragma unroll
    for (int j = 0; j < 4; ++j)
      load_lds16((const char*)Bb + s * 128 + sOf[j], (char*)lB + sDs[j]);
    asm volatile("s_waitcnt vmcnt(0)" ::: "memory");
    BAR(); CFENCE();
#pragma unroll
    for (int kc = 0; kc < 2; ++kc) {
      bf16x8 af[4], bfr[4];
#pragma unroll
      for (int mt = 0; mt < 4; ++mt) {
        int row = wr * 64 + mt * 16 + col;
        af[mt] = *(const bf16x8*)((const char*)lA + row * 128 + (((kc * 4 + g) ^ (row & 7)) << 4));
      }
#pragma unroll
      for (int nt = 0; nt < 4; ++nt) {
        int row = wc * 64 + nt * 16 + col;
        bfr[nt] = *(const bf16x8*)((const char*)lB + row * 128 + (((kc * 4 + g) ^ (row & 7)) << 4));
      }
#pragma unroll
      for (int mt = 0; mt < 4; ++mt)
#pragma unroll
        for (int nt = 0; nt < 4; ++nt)
          acc[mt][nt] = MFMA16(af[mt], bfr[nt], acc[mt][nt]);
    }
  }
  if (epi == 0) {
#pragma unroll
    for (int nt = 0; nt < 4; ++nt) {
      int op = by * 128 + wc * 64 + nt * 16 + col;
      int hh = op >> 6, ii = op & 63;
      float bv = bias[op];
#pragma unroll
      for (int mt = 0; mt < 4; ++mt) {
        int nbase = bx * 128 + wr * 64 + mt * 16 + g * 4;
#pragma unroll
        for (int r = 0; r < 4; ++r)
          outp[((size_t)(hh * 2048 + nbase + r)) * 64 + ii] = f2b((acc[mt][nt][r] + bv) * osc);
      }
    }
  } else {
#pragma unroll
    for (int mt = 0; mt < 4; ++mt)
#pragma unroll
      for (int r = 0; r < 4; ++r) {
        int row = bx * 128 + wr * 64 + mt * 16 + g * 4 + r;
        float bv = bias[row];
#pragma unroll
        for (int nt = 0; nt < 4; ++nt) {
          int cn = by * 128 + wc * 64 + nt * 16 + col;
          outp[(size_t)row * 2048 + cn] = f2b(acc[mt][nt][r] + bv);
        }
      }
  }
}

// ---------------------------------------------------------------- final M-proj GEMM (f32 out)
// 64x128 tile, BK=64, dbuf + counted vmcnt(6) + raw barriers; grid 512 = 2/CU.
// Waves 2x2: wr covers 32 M-rows, wc covers 64 N-cols -> 2x4 frags (16 MFMA/K-tile).
__global__ __launch_bounds__(256, 2) void k_gemmM(
    const u16* __restrict__ A,
    const u16* __restrict__ Bm, long sB,
    const float* __restrict__ bias,
    float* __restrict__ out, long sOut)
{
  __shared__ u16 lA[2][64 * 64];
  __shared__ u16 lB[2][128 * 64];
  int t = threadIdx.x, b = blockIdx.z;
  const u16* Ab = A + (size_t)blockIdx.x * 64 * 256;
  const u16* Bb = Bm + (size_t)b * sB + (size_t)blockIdx.y * 128 * 256;
  int l = t & 63, w = t >> 6, g = l >> 4, col = l & 15;
  int wr = w >> 1, wc = w & 1;
  f32x4 acc[2][4] = {};
  u32 sOfA[2], sDsA[2], sOfB[4], sDsB[4];
#pragma unroll
  for (int j = 0; j < 2; ++j) {
    int ci = t + 256 * j;
    int r = ci >> 3, c = ci & 7;
    sOfA[j] = (u32)(r * 512 + ((c ^ (r & 7)) << 4));
    sDsA[j] = (u32)(ci * 16);
  }
#pragma unroll
  for (int j = 0; j < 4; ++j) {
    int ci = t + 256 * j;
    int r = ci >> 3, c = ci & 7;
    sOfB[j] = (u32)(r * 512 + ((c ^ (r & 7)) << 4));
    sDsB[j] = (u32)(ci * 16);
  }
  auto stage = [&](int buf, int k0) {
#pragma unroll
    for (int j = 0; j < 2; ++j)
      load_lds16((const char*)Ab + k0 * 2 + sOfA[j], (char*)lA[buf] + sDsA[j]);
#pragma unroll
    for (int j = 0; j < 4; ++j)
      load_lds16((const char*)Bb + k0 * 2 + sOfB[j], (char*)lB[buf] + sDsB[j]);
  };
  stage(0, 0);
  for (int s = 0; s < 4; ++s) {
    int cur = s & 1;
    if (s < 3) {
      stage(cur ^ 1, (s + 1) * 64);
      asm volatile("s_waitcnt vmcnt(6)" ::: "memory");
    } else {
      asm volatile("s_waitcnt vmcnt(0)" ::: "memory");
    }
    BAR(); CFENCE();
#pragma unroll
    for (int kc = 0; kc < 2; ++kc) {
      bf16x8 af[2], bfr[4];
#pragma unroll
      for (int mt = 0; mt < 2; ++mt) {
        int row = wr * 32 + mt * 16 + col;
        af[mt] = *(const bf16x8*)((const char*)lA[cur] + row * 128 + (((kc * 4 + g) ^ (row & 7)) << 4));
      }
#pragma unroll
      for (int nt = 0; nt < 4; ++nt) {
        int row = wc * 64 + nt * 16 + col;
        bfr[nt] = *(const bf16x8*)((const char*)lB[cur] + row * 128 + (((kc * 4 + g) ^ (row & 7)) << 4));
      }
#pragma unroll
      for (int mt = 0; mt < 2; ++mt)
#pragma unroll
        for (int nt = 0; nt < 4; ++nt)
          acc[mt][nt] = MFMA16(af[mt], bfr[nt], acc[mt][nt]);
    }
    if (s < 3) { CFENCE(); BAR(); }
  }
  float* o = out + (size_t)b * sOut;
#pragma unroll
  for (int mt = 0; mt < 2; ++mt)
#pragma unroll
    for (int r = 0; r < 4; ++r) {
      int row = blockIdx.x * 64 + wr * 32 + mt * 16 + g * 4 + r;
      float bv = bias[row];
#pragma unroll
      for (int nt = 0; nt < 4; ++nt) {
        int cn = blockIdx.y * 128 + wc * 64 + nt * 16 + col;
        o[(size_t)row * 2048 + cn] = acc[mt][nt][r] + bv;
      }
    }
}

// ---------------------------------------------------------------- flash attention (r13 champion)
// 4 waves x 32 q-rows, grid 512 XCD-swizzled, 4-buffer ring 64KB, counted
// vmcnt, one raw barrier/iter, QK/PV chain-split, exp2-direct softmax.
__global__ __launch_bounds__(256, 2) void k_attn(
    const u16* __restrict__ Qt, const u16* __restrict__ Kt,
    const u16* __restrict__ Vw, u16* __restrict__ Xws)
{
  __shared__ u16 stg[4][2][4096];    // [buf][K|V][64 rows * 64] = 64 KB
  int t = threadIdx.x, l = t & 63;
  int w = t >> 6;
  int hi = l >> 5, col = l & 31;
  int lin = blockIdx.x;
  int xcd = lin & 7, j = lin >> 3;     // j 0..63
  int bh = xcd * 4 + (j >> 4);
  int nb = j & 15;
  int b = bh >> 2, hh = bh & 3;
  const u16* Qb = Qt + ((size_t)(b * 4 + hh) * 2048) * 64;
  const u16* Kb = Kt + ((size_t)(b * 4 + hh) * 2048) * 64;
  const u16* Vb = Vw + ((size_t)(b * 256 + hh * 64)) * 2048;
  int nq = nb * 128 + w * 32 + col;

  bf16x8 qf[4];
#pragma unroll
  for (int ks = 0; ks < 4; ++ks)
    qf[ks] = *(const bf16x8*)&Qb[(size_t)nq * 64 + ks * 16 + hi * 8];

  u32 kSrc[2], vSrc[2], sDst[2];
#pragma unroll
  for (int jj = 0; jj < 2; ++jj) {
    int ci = t + 256 * jj;
    int r = ci >> 3, c = ci & 7;
    u32 sw = (u32)((c ^ ((r >> 1) & 7)) << 4);
    kSrc[jj] = (u32)(r * 128) + sw;
    vSrc[jj] = (u32)(r * 4096) + sw;
    sDst[jj] = (u32)(ci * 16);
  }
  u32 offC[4];
#pragma unroll
  for (int ks = 0; ks < 4; ++ks)
    offC[ks] = (u32)(((2 * ks + hi) ^ ((col >> 1) & 7)) << 4);
  u32 colb = (u32)(col * 128);

  f32x16 xac0a = {}, xac0b = {}, xac1a = {}, xac1b = {};
  float psum = 0.0f, m_run = 0.0f;

  auto stage = [&](int buf, int tile) {
    const char* kb = (const char*)Kb + (size_t)tile * 8192;
    const char* vb = (const char*)Vb + (size_t)tile * 128;
#pragma unroll
    for (int jj = 0; jj < 2; ++jj)
      load_lds16(kb + kSrc[jj], (char*)stg[buf][0] + sDst[jj]);
#pragma unroll
    for (int jj = 0; jj < 2; ++jj)
      load_lds16(vb + vSrc[jj], (char*)stg[buf][1] + sDst[jj]);
  };

  auto do_qk = [&](int buf, f32x16& s0, f32x16& s1) {
    const char* kK = (const char*)stg[buf][0] + colb;
    f32x16 s0a = {}, s0b = {}, s1a = {}, s1b = {};
    __builtin_amdgcn_s_setprio(1);
#pragma unroll
    for (int ks = 0; ks < 2; ++ks) {
      bf16x8 kf0 = *(const bf16x8*)(kK + offC[ks]);
      bf16x8 kf1 = *(const bf16x8*)(kK + 4096 + offC[ks]);
      s0a = MFMA32(kf0, qf[ks], s0a);
      s1a = MFMA32(kf1, qf[ks], s1a);
      bf16x8 kf0b = *(const bf16x8*)(kK + offC[ks + 2]);
      bf16x8 kf1b = *(const bf16x8*)(kK + 4096 + offC[ks + 2]);
      s0b = MFMA32(kf0b, qf[ks + 2], s0b);
      s1b = MFMA32(kf1b, qf[ks + 2], s1b);
    }
    __builtin_amdgcn_s_setprio(0);
    s0 = s0a + s0b;
    s1 = s1a + s1b;
  };

  auto do_sm_pv = [&](int buf, const f32x16& s0, const f32x16& s1) {
    bf16x8 pf[4];
    float ps = 0.0f;
#pragma unroll
    for (int mt = 0; mt < 2; ++mt) {
      const f32x16& sc = mt ? s1 : s0;
      float p[16];
      if (m_run == 0.0f) {
#pragma unroll
        for (int r = 0; r < 16; ++r) p[r] = __builtin_amdgcn_exp2f(sc[r]);
      } else {
#pragma unroll
        for (int r = 0; r < 16; ++r) p[r] = __builtin_amdgcn_exp2f(sc[r] - m_run);
      }
      ps += ((((p[0] + p[1]) + (p[2] + p[3])) + ((p[4] + p[5]) + (p[6] + p[7])))
          + (((p[8] + p[9]) + (p[10] + p[11])) + ((p[12] + p[13]) + (p[14] + p[15]))));
      u32 A0 = pkbf(p[0],  p[1]),  B0 = pkbf(p[2],  p[3]);
      u32 A1 = pkbf(p[4],  p[5]),  B1 = pkbf(p[6],  p[7]);
      u32 A2 = pkbf(p[8],  p[9]),  B2 = pkbf(p[10], p[11]);
      u32 A3 = pkbf(p[12], p[13]), B3 = pkbf(p[14], p[15]);
      asm("v_permlane32_swap_b32 %0, %1" : "+v"(A0), "+v"(A1));
      asm("v_permlane32_swap_b32 %0, %1" : "+v"(B0), "+v"(B1));
      asm("v_permlane32_swap_b32 %0, %1" : "+v"(A2), "+v"(A3));
      asm("v_permlane32_swap_b32 %0, %1" : "+v"(B2), "+v"(B3));
      union { u32 u[4]; bf16x8 v; } f0, f1;
      f0.u[0] = A0; f0.u[1] = B0; f0.u[2] = A1; f0.u[3] = B1;
      f1.u[0] = A2; f1.u[1] = B2; f1.u[2] = A3; f1.u[3] = B3;
      pf[mt * 2 + 0] = f0.v;
      pf[mt * 2 + 1] = f1.v;
    }
    psum += ps;
    const char* kV = (const char*)stg[buf][1] + colb;
    __builtin_amdgcn_s_setprio(1);
#pragma unroll
    for (int S = 0; S < 2; ++S) {
      bf16x8 vf0 = *(const bf16x8*)(kV + offC[S]);
      bf16x8 vf1 = *(const bf16x8*)(kV + 4096 + offC[S]);
      xac0a = MFMA32(vf0, pf[S], xac0a);
      xac1a = MFMA32(vf1, pf[S], xac1a);
      bf16x8 vf0b = *(const bf16x8*)(kV + offC[S + 2]);
      bf16x8 vf1b = *(const bf16x8*)(kV + 4096 + offC[S + 2]);
      xac0b = MFMA32(vf0b, pf[S + 2], xac0b);
      xac1b = MFMA32(vf1b, pf[S + 2], xac1b);
    }
    __builtin_amdgcn_s_setprio(0);
  };

  stage(0, 0);
  stage(1, 1);
  asm volatile("s_waitcnt vmcnt(4)" ::: "memory");
  BAR(); CFENCE();
  f32x16 sA0, sA1;
  do_qk(0, sA0, sA1);
  stage(2, 2);

  for (int it = 0; it < 31; ++it) {
    if (__any(psum > 16777216.0f)) {
      const float ds = 5.9604644775390625e-8f;   // 2^-24
      xac0a *= ds; xac0b *= ds; xac1a *= ds; xac1b *= ds; psum *= ds;
      m_run += 24.0f;
    }
    if (it < 30) {
      asm volatile("s_waitcnt vmcnt(4)" ::: "memory");
    } else {
      asm volatile("s_waitcnt vmcnt(0)" ::: "memory");
    }
    BAR(); CFENCE();
    if (it + 3 <= 31) stage((it + 3) & 3, it + 3);
    f32x16 sB0, sB1;
    do_qk((it + 1) & 3, sB0, sB1);
    do_sm_pv(it & 3, sA0, sA1);
    sA0 = sB0; sA1 = sB1;
  }
  if (__any(psum > 16777216.0f)) {
    const float ds = 5.9604644775390625e-8f;
    xac0a *= ds; xac0b *= ds; xac1a *= ds; xac1b *= ds; psum *= ds;
    m_run += 24.0f;
  }
  do_sm_pv(31 & 3, sA0, sA1);

  f32x16 xac0 = xac0a + xac0b;
  f32x16 xac1 = xac1a + xac1b;
  psum += __shfl_xor(psum, 32);
  float inv = 1.0f / psum;
  u16* Ob = Xws + (size_t)b * 2048 * 256 + (size_t)nq * 256 + hh * 64;
#pragma unroll
  for (int it2 = 0; it2 < 2; ++it2) {
    const f32x16& xa = it2 ? xac1 : xac0;
#pragma unroll
    for (int rq = 0; rq < 4; ++rq) {
      float v0 = xa[4 * rq + 0] * inv;
      float v1 = xa[4 * rq + 1] * inv;
      float v2 = xa[4 * rq + 2] * inv;
      float v3 = xa[4 * rq + 3] * inv;
      u32x2 w2; w2[0] = pkbf(v0, v1); w2[1] = pkbf(v2, v3);
      *(u32x2*)&Ob[it2 * 32 + 8 * rq + 4 * hi] = w2;
    }
  }
}

// ---------------------------------------------------------------- launch
extern "C" void kernel_launch(void* const* d_in, const int* in_sizes, int n_in,
                              void* d_out, int out_size, void* d_ws, size_t ws_size,
                              hipStream_t stream)
{
  const float* q_in = (const float*)d_in[0];
  const float* k_in = (const float*)d_in[1];
  const float* v_in = (const float*)d_in[2];
  const float* w_q  = (const float*)d_in[3];
  const float* b_q  = (const float*)d_in[4];
  const float* w_k  = (const float*)d_in[5];
  const float* b_k  = (const float*)d_in[6];
  const float* w_v  = (const float*)d_in[7];
  const float* b_v  = (const float*)d_in[8];
  const float* w_m  = (const float*)d_in[9];
  const float* b_m  = (const float*)d_in[10];

  char* ws = (char*)d_ws;
  u16* XT_Q = (u16*)(ws + 0);           // [8][2048][256] bf16; reused as attn out
  u16* XT_K = (u16*)(ws + 8388608);
  u16* XT_V = (u16*)(ws + 16777216);
  u16* QT   = (u16*)(ws + 25165824);    // [8][4][2048][64]
  u16* KT   = (u16*)(ws + 33554432);
  u16* VW   = (u16*)(ws + 41943040);    // [8][256][2048]
  u16* WQ   = (u16*)(ws + 50331648);
  u16* WK   = (u16*)(ws + 50462720);
  u16* WV   = (u16*)(ws + 50593792);
  u16* WM   = (u16*)(ws + 50724864);
  float* BQ = (float*)(ws + 50855936);
  float* BK = (float*)(ws + 50856960);
  float* BV = (float*)(ws + 50857984);

  k_pre<<<dim3(4352), 256, 0, stream>>>(q_in, k_in, v_in, w_q, w_k, w_v, w_m,
                                        b_q, b_k, b_v, XT_Q, XT_K, XT_V,
                                        WQ, WK, WV, WM, BQ, BK, BV);
  k_gemm3<<<dim3(768), 256, 0, stream>>>(XT_Q, XT_K, XT_V, WQ, WK, WV,
                                         BQ, BK, BV, QT, KT, VW);
  k_attn<<<dim3(512), 256, 0, stream>>>(QT, KT, VW, XT_Q);
  k_gemmM<<<dim3(4, 16, 8), 256, 0, stream>>>(WM, XT_Q, 2048L * 256, b_m,
                                              (float*)d_out, 256L * 2048);
}